// Round 8
// baseline (141.465 us; speedup 1.0000x reference)
//
#include <hip/hip_runtime.h>

#define S 2048
#define D 128
#define BATCH 8
#define KSTR 136   // K LDS row stride (halves)
#define VSTR 72    // V^T LDS row stride (halves)
#define QSZ 35840  // per-quarter LDS: K 64*KSTR*2 + V 128*VSTR*2

typedef _Float16 half8 __attribute__((ext_vector_type(8)));
typedef _Float16 half4_t __attribute__((ext_vector_type(4)));
typedef float f4 __attribute__((ext_vector_type(4)));

__device__ __forceinline__ half8 cvt8(f4 a, f4 b) {
    half8 h;
    h[0] = (_Float16)a[0]; h[1] = (_Float16)a[1];
    h[2] = (_Float16)a[2]; h[3] = (_Float16)a[3];
    h[4] = (_Float16)b[0]; h[5] = (_Float16)b[1];
    h[6] = (_Float16)b[2]; h[7] = (_Float16)b[3];
    return h;
}

// ---- fused prep: K cast fp16, V transpose -> vt[b][d][t] fp16, and per-chunk
// V column-sum partials (NO atomics, NO memset needed). 512 blocks, 32 rows each.
__global__ __launch_bounds__(256) void k_prep(const float* __restrict__ kin,
                                              const float* __restrict__ v,
                                              _Float16* __restrict__ kh,
                                              _Float16* __restrict__ vt,
                                              float* __restrict__ part) {
    int bid = blockIdx.x;
    int b = bid & 7, c = bid >> 3, tid = threadIdx.x;   // c: 0..63, 32 rows each
    size_t off = ((size_t)b * S + c * 32) * D;
    #pragma unroll
    for (int p = 0; p < 2; ++p) {
        size_t i = (size_t)p * 2048 + tid * 8;
        f4 a = *(const f4*)(kin + off + i);
        f4 bb = *(const f4*)(kin + off + i + 4);
        *(half8*)(kh + off + i) = cvt8(a, bb);
    }
    __shared__ float tile[32 * 132];
    __shared__ f4 sred[256][2];
    f4 a0 = {0.f, 0.f, 0.f, 0.f}, a1 = {0.f, 0.f, 0.f, 0.f};
    int d0 = (tid & 15) * 8;
    #pragma unroll
    for (int p = 0; p < 2; ++p) {
        int t = p * 16 + (tid >> 4);
        f4 x = *(const f4*)(v + off + (size_t)t * D + d0);
        f4 y = *(const f4*)(v + off + (size_t)t * D + d0 + 4);
        a0 += x; a1 += y;
        *(f4*)&tile[t * 132 + d0] = x;
        *(f4*)&tile[t * 132 + d0 + 4] = y;
    }
    sred[tid][0] = a0; sred[tid][1] = a1;
    __syncthreads();
    if (tid < 16) {     // per-chunk partial colsum -> plain stores, no atomics
        f4 s0 = sred[tid][0], s1 = sred[tid][1];
        for (int g = 1; g < 16; ++g) { s0 += sred[g * 16 + tid][0]; s1 += sred[g * 16 + tid][1]; }
        float* dst = part + ((size_t)b * 64 + c) * 128 + tid * 8;
        *(f4*)dst = s0;
        *(f4*)(dst + 4) = s1;
    }
    int u = tid & 3, dd = tid >> 2;                    // u: 8 t's each, dd: 0..63
    #pragma unroll
    for (int pass = 0; pass < 2; ++pass) {
        int d = pass * 64 + dd;
        half8 h;
        #pragma unroll
        for (int i = 0; i < 8; ++i) h[i] = (_Float16)tile[(u * 8 + i) * 132 + d];
        *(half8*)(vt + ((size_t)(b * D + d)) * S + c * 32 + u * 8) = h;
    }
}

// ---- main: flash attention with INTRA-BLOCK key-split. One 1024-thread block
// (16 waves = 4 key-quarters x 4 row-waves) owns one (b, mg) 64-row group.
// Quarter q processes tiles kt = q, q+4, ... into its OWN LDS K/V buffer
// (4 x 35.8 KB = 143 KB) with the proven register-prefetch staging loop —
// serial chain <= 8 steps (vs 32 at NS=1). Uniform trip count + unconditional
// barriers keep the block-wide sync balanced. 4-way combine = proven LDS-atomic
// epilogue overlaid on quarter-0 staging. b = bid&7 restores XCD L2 affinity.
__global__ __launch_bounds__(1024, 4) void k_attn(
    const float* __restrict__ q, const _Float16* __restrict__ kh,
    const _Float16* __restrict__ vt, const int* __restrict__ el,
    const float* __restrict__ part, float* __restrict__ out) {
    int bid = blockIdx.x;
    int b = bid & 7, mg = bid >> 3;
    int Lb = el[b], m0 = mg * 64;
    int tid = threadIdx.x;
    const float inv_s = 1.0f / (float)S;

    __shared__ __align__(16) char smem[4 * QSZ];      // 143360 B

    if (m0 >= Lb) {
        // whole group invalid -> out = colmean(V): reduce 64 prep partials
        float* vsum0 = (float*)smem;
        if (tid < 128) {
            float s = 0.f;
            const float* pp = part + (size_t)b * 64 * 128 + tid;
            #pragma unroll 4
            for (int c = 0; c < 64; ++c) s += pp[c * 128];
            vsum0[tid] = s * inv_s;
        }
        __syncthreads();
        int r = tid >> 4, d0 = (tid & 15) * 8;        // 64 rows x 128 cols
        float* orow = out + ((size_t)b * S + m0 + r) * D + d0;
        *(f4*)orow = *(const f4*)(vsum0 + d0);
        *(f4*)(orow + 4) = *(const f4*)(vsum0 + d0 + 4);
        return;
    }
    int nkt = (Lb + 63) >> 6;
    int NT = (nkt + 3) >> 2;           // uniform per-quarter step count

    int q4 = tid >> 8, tid4 = tid & 255;   // key-quarter, thread within quarter
    int lane = tid & 63, w4 = tid4 >> 6;   // row-wave within quarter
    int col = lane & 15, quad = lane >> 4;

    _Float16* Kh = (_Float16*)(smem + q4 * QSZ);
    _Float16* Vt = (_Float16*)(smem + q4 * QSZ + 17408);
    float* cmb  = (float*)smem;                 // overlay: 64 x 132 f32 = 33792 B
    float* psb  = (float*)(smem + 33792);       // 64 f32
    float* vsum = (float*)(smem + 34048);       // 128 f32

    // Q frags (B-operand of the S^T MFMA), fp32 -> fp16 with 1/sqrt(D).
    // The 4 quarters load the same rows (L1/L2 hit after first).
    const float scale = 0.0883883476483184f;
    half8 qf[4];
    {
        const float* qb = q + ((size_t)b * S + m0 + w4 * 16 + col) * D;
        #pragma unroll
        for (int kc = 0; kc < 4; ++kc) {
            f4 a = *(const f4*)(qb + kc * 32 + quad * 8);
            f4 b2 = *(const f4*)(qb + kc * 32 + quad * 8 + 4);
            a *= scale; b2 *= scale;
            qf[kc] = cvt8(a, b2);
        }
    }

    f4 O[8];
    #pragma unroll
    for (int i = 0; i < 8; ++i) O[i] = (f4){0.f, 0.f, 0.f, 0.f};
    float ps = 0.f;

    int kr = tid4 >> 4, kc8 = (tid4 & 15) << 3;   // K stage: 4 rows/thread of 64
    int vr = tid4 >> 3, vc8 = (tid4 & 7) << 3;    // V stage: 4 d-rows/thread of 128
    const _Float16* kb_ = kh + (size_t)b * S * D;
    const _Float16* vb_ = vt + (size_t)b * D * S;

    half8 kreg[4], vreg[4];
    if (q4 < nkt) {   // stage this quarter's first tile (kt = q4)
        int t0 = q4 * 64;
        #pragma unroll
        for (int p = 0; p < 4; ++p)
            kreg[p] = *(const half8*)(kb_ + (size_t)(t0 + p * 16 + kr) * D + kc8);
        #pragma unroll
        for (int p = 0; p < 4; ++p)
            vreg[p] = *(const half8*)(vb_ + (size_t)(p * 32 + vr) * S + t0 + vc8);
        #pragma unroll
        for (int p = 0; p < 4; ++p)
            *(half8*)&Kh[(p * 16 + kr) * KSTR + kc8] = kreg[p];
        #pragma unroll
        for (int p = 0; p < 4; ++p)
            *(half8*)&Vt[(p * 32 + vr) * VSTR + vc8] = vreg[p];
    }
    __syncthreads();

    for (int s = 0; s < NT; ++s) {
        int kt = s * 4 + q4;
        bool valid = kt < nkt;             // per-quarter
        bool morestep = (s + 1) < NT;      // block-uniform
        int ktn = kt + 4;
        bool vnext = ktn < nkt;

        if (morestep && vnext) {  // prefetch next tile into regs, overlaps compute
            int tn = ktn * 64;
            #pragma unroll
            for (int p = 0; p < 4; ++p)
                kreg[p] = *(const half8*)(kb_ + (size_t)(tn + p * 16 + kr) * D + kc8);
            #pragma unroll
            for (int p = 0; p < 4; ++p)
                vreg[p] = *(const half8*)(vb_ + (size_t)(p * 32 + vr) * S + tn + vc8);
        }

        if (valid) {
            int t0 = kt * 64;
            #pragma unroll
            for (int nt = 0; nt < 4; ++nt) {
                // S^T = K Q^T: C[key = nt*16 + quad*4 + r][qrow = col]
                f4 sa = {0.f, 0.f, 0.f, 0.f};
                __builtin_amdgcn_s_setprio(1);
                #pragma unroll
                for (int kc = 0; kc < 4; ++kc) {
                    half8 kf = *(const half8*)&Kh[(nt * 16 + col) * KSTR + kc * 32 + quad * 8];
                    sa = __builtin_amdgcn_mfma_f32_16x16x32_f16(kf, qf[kc], sa, 0, 0, 0);
                }
                __builtin_amdgcn_s_setprio(0);
                // exp with key-validity mask; P = A-frag of 16x16x16 (k=quad*4+r)
                int tq = t0 + nt * 16 + quad * 4;
                half4_t ph;
                #pragma unroll
                for (int r = 0; r < 4; ++r) {
                    float e = (tq + r < Lb) ? __expf(fminf(sa[r], 10.0f)) : 0.f;
                    ps += e;
                    ph[r] = (_Float16)e;
                }
                // O += P V for this 16-key group
                __builtin_amdgcn_s_setprio(1);
                #pragma unroll
                for (int dt = 0; dt < 8; ++dt) {
                    half4_t vf = *(const half4_t*)&Vt[(dt * 16 + col) * VSTR + nt * 16 + quad * 4];
                    O[dt] = __builtin_amdgcn_mfma_f32_16x16x16f16(ph, vf, O[dt], 0, 0, 0);
                }
                __builtin_amdgcn_s_setprio(0);
            }
        }

        if (morestep) {                    // uniform barriers; guarded writes
            __syncthreads();
            if (vnext) {
                #pragma unroll
                for (int p = 0; p < 4; ++p)
                    *(half8*)&Kh[(p * 16 + kr) * KSTR + kc8] = kreg[p];
                #pragma unroll
                for (int p = 0; p < 4; ++p)
                    *(half8*)&Vt[(p * 32 + vr) * VSTR + vc8] = vreg[p];
            }
            __syncthreads();
        }
    }

    // ---- epilogue: 4-way combine in LDS (overlay on staging), then write ----
    __syncthreads();                   // all staging reads done; LDS reusable
    ps += __shfl_xor(ps, 16, 64);      // row-sum over this quarter's keys
    ps += __shfl_xor(ps, 32, 64);

    bool tail = (m0 + 64 > Lb);        // block-uniform
    if (tail && tid < 128) {           // colmean for rows >= L in this group
        float s = 0.f;
        const float* pp = part + (size_t)b * 64 * 128 + tid;
        #pragma unroll 4
        for (int c = 0; c < 64; ++c) s += pp[c * 128];
        vsum[tid] = s * inv_s;
    }
    if (q4 == 0) {                     // quarter 0 seeds the combine buffer
        #pragma unroll
        for (int dt = 0; dt < 8; ++dt)
            #pragma unroll
            for (int r = 0; r < 4; ++r)
                cmb[(w4 * 16 + quad * 4 + r) * 132 + dt * 16 + col] = O[dt][r];
        if (quad == 0) psb[w4 * 16 + col] = ps;
    }
    __syncthreads();
    if (q4 != 0) {                     // quarters 1-3 accumulate (LDS atomics)
        #pragma unroll
        for (int dt = 0; dt < 8; ++dt)
            #pragma unroll
            for (int r = 0; r < 4; ++r)
                atomicAdd(&cmb[(w4 * 16 + quad * 4 + r) * 132 + dt * 16 + col], O[dt][r]);
        if (quad == 0) atomicAdd(&psb[w4 * 16 + col], ps);
    }
    __syncthreads();
    if (q4 == 0) {                     // quarter 0 normalizes + writes output
        float pst = psb[w4 * 16 + col];          // total row-sum for qrow = col
        float l4[4];
        #pragma unroll
        for (int r = 0; r < 4; ++r) l4[r] = __shfl(pst, quad * 4 + r, 64);

        float smv[8] = {};
        if (tail) {
            #pragma unroll
            for (int dt = 0; dt < 8; ++dt) smv[dt] = vsum[dt * 16 + col];
        }
        #pragma unroll
        for (int r = 0; r < 4; ++r) {
            int row = m0 + w4 * 16 + quad * 4 + r;
            float inv = 1.0f / l4[r];
            float* orow = out + ((size_t)b * S + row) * D;
            #pragma unroll
            for (int dt = 0; dt < 8; ++dt) {
                float val = (row < Lb)
                    ? cmb[(w4 * 16 + quad * 4 + r) * 132 + dt * 16 + col] * inv
                    : smv[dt];
                orow[dt * 16 + col] = val;
            }
        }
    }
}

extern "C" void kernel_launch(void* const* d_in, const int* in_sizes, int n_in,
                              void* d_out, int out_size, void* d_ws, size_t ws_size,
                              hipStream_t stream) {
    const float* q = (const float*)d_in[0];
    const float* k = (const float*)d_in[1];
    const float* v = (const float*)d_in[2];
    const int* el = (const int*)d_in[3];
    float* out = (float*)d_out;

    const size_t SZ_PART = (size_t)BATCH * 64 * 128 * 4;  // 256 KB partial colsums
    const size_t SZ_HALF = (size_t)BATCH * D * S * 2;     // 4.19 MB each
    float* part = (float*)d_ws;
    _Float16* kh = (_Float16*)((char*)d_ws + SZ_PART);
    _Float16* vt = (_Float16*)((char*)d_ws + SZ_PART + SZ_HALF);

    k_prep<<<dim3(512), 256, 0, stream>>>(k, v, kh, vt, part);
    k_attn<<<dim3(256), 1024, 0, stream>>>(q, kh, vt, el, part, out);
}

// Round 9
// 110.569 us; speedup vs baseline: 1.2794x; 1.2794x over previous
//
#include <hip/hip_runtime.h>

#define S 2048
#define D 128
#define BATCH 8
#define NS 4       // key-split factor (separate blocks, combined in k_comb)
#define KSTR 136   // K LDS row stride (halves)
#define VSTR 72    // V^T LDS row stride (halves)

typedef _Float16 half8 __attribute__((ext_vector_type(8)));
typedef _Float16 half4_t __attribute__((ext_vector_type(4)));
typedef float f4 __attribute__((ext_vector_type(4)));

__device__ __forceinline__ half8 cvt8(f4 a, f4 b) {
    half8 h;
    h[0] = (_Float16)a[0]; h[1] = (_Float16)a[1];
    h[2] = (_Float16)a[2]; h[3] = (_Float16)a[3];
    h[4] = (_Float16)b[0]; h[5] = (_Float16)b[1];
    h[6] = (_Float16)b[2]; h[7] = (_Float16)b[3];
    return h;
}

// ---- fused prep: K cast fp16, V transpose -> vt[b][d][t] fp16, and per-chunk
// V column-sum partials (NO atomics, NO memset needed). 512 blocks, 32 rows each.
__global__ __launch_bounds__(256) void k_prep(const float* __restrict__ kin,
                                              const float* __restrict__ v,
                                              _Float16* __restrict__ kh,
                                              _Float16* __restrict__ vt,
                                              float* __restrict__ vpart) {
    int bid = blockIdx.x;
    int b = bid & 7, c = bid >> 3, tid = threadIdx.x;   // c: 0..63, 32 rows each
    size_t off = ((size_t)b * S + c * 32) * D;
    #pragma unroll
    for (int p = 0; p < 2; ++p) {
        size_t i = (size_t)p * 2048 + tid * 8;
        f4 a = *(const f4*)(kin + off + i);
        f4 bb = *(const f4*)(kin + off + i + 4);
        *(half8*)(kh + off + i) = cvt8(a, bb);
    }
    __shared__ float tile[32 * 132];
    __shared__ f4 sred[256][2];
    f4 a0 = {0.f, 0.f, 0.f, 0.f}, a1 = {0.f, 0.f, 0.f, 0.f};
    int d0 = (tid & 15) * 8;
    #pragma unroll
    for (int p = 0; p < 2; ++p) {
        int t = p * 16 + (tid >> 4);
        f4 x = *(const f4*)(v + off + (size_t)t * D + d0);
        f4 y = *(const f4*)(v + off + (size_t)t * D + d0 + 4);
        a0 += x; a1 += y;
        *(f4*)&tile[t * 132 + d0] = x;
        *(f4*)&tile[t * 132 + d0 + 4] = y;
    }
    sred[tid][0] = a0; sred[tid][1] = a1;
    __syncthreads();
    if (tid < 16) {     // per-chunk partial colsum -> plain stores, no atomics
        f4 s0 = sred[tid][0], s1 = sred[tid][1];
        for (int g = 1; g < 16; ++g) { s0 += sred[g * 16 + tid][0]; s1 += sred[g * 16 + tid][1]; }
        float* dst = vpart + ((size_t)b * 64 + c) * 128 + tid * 8;
        *(f4*)dst = s0;
        *(f4*)(dst + 4) = s1;
    }
    int u = tid & 3, dd = tid >> 2;                    // u: 8 t's each, dd: 0..63
    #pragma unroll
    for (int pass = 0; pass < 2; ++pass) {
        int d = pass * 64 + dd;
        half8 h;
        #pragma unroll
        for (int i = 0; i < 8; ++i) h[i] = (_Float16)tile[(u * 8 + i) * 132 + d];
        *(half8*)(vt + ((size_t)(b * D + d)) * S + c * 32 + u * 8) = h;
    }
}

// ---- main: flash attention, NS=4 key-split across SEPARATE 256-thread
// blocks (the proven fast structure: chain <= 8 steps, 4 blocks/CU all
// resident, concurrent blocks overlap latency). Static mapping b = bid&7
// (XCD L2 affinity with prep), mg = (bid>>3)&31, j = bid>>8. Blocks with
// j >= nkt write ZERO partials so k_comb can sum all NS unconditionally.
__global__ __launch_bounds__(256, 4) void k_attn(
    const float* __restrict__ q, const _Float16* __restrict__ kh,
    const _Float16* __restrict__ vt, const int* __restrict__ el,
    _Float16* __restrict__ part, float* __restrict__ stats) {
    int bid = blockIdx.x;
    int b = bid & 7, mg = (bid >> 3) & 31, j = bid >> 8;
    int Lb = el[b], m0 = mg * 64;
    if (m0 >= Lb) return;              // k_comb handles these rows (colmean)
    int nkt = (Lb + 63) >> 6;

    int tid = threadIdx.x, lane = tid & 63, w = tid >> 6;
    int col = lane & 15, quad = lane >> 4;

    __shared__ _Float16 Kh[64 * KSTR];
    __shared__ _Float16 Vt[128 * VSTR];

    // Q frags (B-operand of the S^T MFMA), fp32 -> fp16 with 1/sqrt(D)
    const float scale = 0.0883883476483184f;
    half8 qf[4];
    {
        const float* qb = q + ((size_t)b * S + m0 + w * 16 + col) * D;
        #pragma unroll
        for (int kc = 0; kc < 4; ++kc) {
            f4 a = *(const f4*)(qb + kc * 32 + quad * 8);
            f4 b2 = *(const f4*)(qb + kc * 32 + quad * 8 + 4);
            a *= scale; b2 *= scale;
            qf[kc] = cvt8(a, b2);
        }
    }

    f4 O[8];
    #pragma unroll
    for (int i = 0; i < 8; ++i) O[i] = (f4){0.f, 0.f, 0.f, 0.f};
    float ps = 0.f;

    int kr = tid >> 4, kc8 = (tid & 15) << 3;
    int vr = tid >> 3, vc8 = (tid & 7) << 3;
    const _Float16* kb_ = kh + (size_t)b * S * D;
    const _Float16* vb_ = vt + (size_t)b * D * S;

    if (j < nkt) {
        half8 kreg[4], vreg[4];
        {   // stage tile j
            int t0 = j * 64;
            #pragma unroll
            for (int p = 0; p < 4; ++p)
                kreg[p] = *(const half8*)(kb_ + (size_t)(t0 + p * 16 + kr) * D + kc8);
            #pragma unroll
            for (int p = 0; p < 4; ++p)
                vreg[p] = *(const half8*)(vb_ + (size_t)(p * 32 + vr) * S + t0 + vc8);
            #pragma unroll
            for (int p = 0; p < 4; ++p)
                *(half8*)&Kh[(p * 16 + kr) * KSTR + kc8] = kreg[p];
            #pragma unroll
            for (int p = 0; p < 4; ++p)
                *(half8*)&Vt[(p * 32 + vr) * VSTR + vc8] = vreg[p];
        }
        __syncthreads();

        for (int kt = j; kt < nkt; kt += NS) {
            int t0 = kt * 64;
            bool hasnext = (kt + NS) < nkt;
            if (hasnext) {  // prefetch next tile into regs, overlaps compute
                int tn = t0 + NS * 64;
                #pragma unroll
                for (int p = 0; p < 4; ++p)
                    kreg[p] = *(const half8*)(kb_ + (size_t)(tn + p * 16 + kr) * D + kc8);
                #pragma unroll
                for (int p = 0; p < 4; ++p)
                    vreg[p] = *(const half8*)(vb_ + (size_t)(p * 32 + vr) * S + tn + vc8);
            }

            #pragma unroll
            for (int nt = 0; nt < 4; ++nt) {
                // S^T = K Q^T: C[key = nt*16 + quad*4 + r][qrow = col]
                f4 sa = {0.f, 0.f, 0.f, 0.f};
                __builtin_amdgcn_s_setprio(1);
                #pragma unroll
                for (int kc = 0; kc < 4; ++kc) {
                    half8 kf = *(const half8*)&Kh[(nt * 16 + col) * KSTR + kc * 32 + quad * 8];
                    sa = __builtin_amdgcn_mfma_f32_16x16x32_f16(kf, qf[kc], sa, 0, 0, 0);
                }
                __builtin_amdgcn_s_setprio(0);
                // exp with key-validity mask; P = A-frag of 16x16x16 (k=quad*4+r)
                int tq = t0 + nt * 16 + quad * 4;
                half4_t ph;
                #pragma unroll
                for (int r = 0; r < 4; ++r) {
                    float e = (tq + r < Lb) ? __expf(fminf(sa[r], 10.0f)) : 0.f;
                    ps += e;
                    ph[r] = (_Float16)e;
                }
                // O += P V for this 16-key group
                __builtin_amdgcn_s_setprio(1);
                #pragma unroll
                for (int dt = 0; dt < 8; ++dt) {
                    half4_t vf = *(const half4_t*)&Vt[(dt * 16 + col) * VSTR + nt * 16 + quad * 4];
                    O[dt] = __builtin_amdgcn_mfma_f32_16x16x16f16(ph, vf, O[dt], 0, 0, 0);
                }
                __builtin_amdgcn_s_setprio(0);
            }

            if (hasnext) {
                __syncthreads();
                #pragma unroll
                for (int p = 0; p < 4; ++p)
                    *(half8*)&Kh[(p * 16 + kr) * KSTR + kc8] = kreg[p];
                #pragma unroll
                for (int p = 0; p < 4; ++p)
                    *(half8*)&Vt[(p * 32 + vr) * VSTR + vc8] = vreg[p];
                __syncthreads();
            }
        }
    }

    // epilogue: reduce l over quads (2 shfls), write fp16 partials + stats.
    // Unconditional: j >= nkt blocks write zeros (k_comb sums all NS splits).
    ps += __shfl_xor(ps, 16, 64);
    ps += __shfl_xor(ps, 32, 64);
    size_t pbase = (size_t)(j * BATCH + b) * S;
    #pragma unroll
    for (int dt = 0; dt < 8; ++dt)
        #pragma unroll
        for (int r = 0; r < 4; ++r) {
            int row = m0 + w * 16 + quad * 4 + r;
            part[(pbase + row) * D + dt * 16 + col] = (_Float16)O[dt][r];
        }
    if (quad == 0) stats[pbase + m0 + w * 16 + col] = ps;
}

// ---- combine: sum NS splits, normalize; rows >= L get colmean(V) from the
// prep partial colsums (no atomics anywhere). b = bid&7 keeps the partial
// reads XCD-L2-local with k_attn's writes.
__global__ __launch_bounds__(256) void k_comb(
    const _Float16* __restrict__ part, const float* __restrict__ stats,
    const float* __restrict__ vpart, const int* __restrict__ el,
    float* __restrict__ out) {
    int bid = blockIdx.x;
    int b = bid & 7, mg = bid >> 3;
    int L = el[b], m0 = mg * 64, tid = threadIdx.x;
    const float inv_s = 1.0f / (float)S;
    __shared__ float vsum[128];

    bool tail = (m0 + 64 > L);         // block-uniform
    if (tail) {                        // colmean(V) = reduce 64 prep partials
        if (tid < 128) {
            float s = 0.f;
            const float* pp = vpart + (size_t)b * 64 * 128 + tid;
            #pragma unroll 4
            for (int c = 0; c < 64; ++c) s += pp[c * 128];
            vsum[tid] = s * inv_s;
        }
        __syncthreads();
    }

    int r = tid >> 2, d0 = (tid & 3) * 32;
    int srow = m0 + r;
    float* orow = out + ((size_t)b * S + srow) * D + d0;
    if (srow >= L) {
        #pragma unroll
        for (int sg = 0; sg < 8; ++sg)
            *(f4*)(orow + sg * 4) = *(const f4*)(vsum + d0 + sg * 4);
        return;
    }
    size_t rbase = (size_t)b * S + srow;
    const size_t step = (size_t)BATCH * S;
    float l = 0.f;
    #pragma unroll
    for (int jj = 0; jj < NS; ++jj) l += stats[rbase + jj * step];
    float inv = 1.0f / l;
    f4 o[8];
    #pragma unroll
    for (int i = 0; i < 8; ++i) o[i] = (f4){0.f, 0.f, 0.f, 0.f};
    #pragma unroll
    for (int jj = 0; jj < NS; ++jj) {
        const half8* p = (const half8*)(part + (rbase + jj * step) * D + d0);
        #pragma unroll
        for (int sg = 0; sg < 4; ++sg) {
            half8 h = p[sg];
            f4 x0 = {(float)h[0], (float)h[1], (float)h[2], (float)h[3]};
            f4 x1 = {(float)h[4], (float)h[5], (float)h[6], (float)h[7]};
            o[sg * 2] += x0;
            o[sg * 2 + 1] += x1;
        }
    }
    #pragma unroll
    for (int i = 0; i < 8; ++i) *(f4*)(orow + i * 4) = o[i] * inv;
}

extern "C" void kernel_launch(void* const* d_in, const int* in_sizes, int n_in,
                              void* d_out, int out_size, void* d_ws, size_t ws_size,
                              hipStream_t stream) {
    const float* q = (const float*)d_in[0];
    const float* k = (const float*)d_in[1];
    const float* v = (const float*)d_in[2];
    const int* el = (const int*)d_in[3];
    float* out = (float*)d_out;

    const size_t SZ_VPART = (size_t)BATCH * 64 * 128 * 4;     // 256 KB
    const size_t SZ_HALF  = (size_t)BATCH * D * S * 2;        // 4.19 MB each
    const size_t SZ_STAT  = (size_t)NS * BATCH * S * 4;       // 256 KB
    float* vpart = (float*)d_ws;
    _Float16* kh = (_Float16*)((char*)d_ws + SZ_VPART);
    _Float16* vt = (_Float16*)((char*)d_ws + SZ_VPART + SZ_HALF);
    float* stats = (float*)((char*)d_ws + SZ_VPART + 2 * SZ_HALF);
    _Float16* part = (_Float16*)((char*)d_ws + SZ_VPART + 2 * SZ_HALF + SZ_STAT);

    k_prep<<<dim3(512), 256, 0, stream>>>(k, v, kh, vt, vpart);
    k_attn<<<dim3(1024), 256, 0, stream>>>(q, kh, vt, el, part, stats);
    k_comb<<<dim3(256), 256, 0, stream>>>(part, stats, vpart, el, out);
}